// Round 2
// 266.231 us; speedup vs baseline: 1.0343x; 1.0343x over previous
//
#include <hip/hip_runtime.h>

#define B_BATCH 128
#define N_RX 34
#define IMG 512
#define N_CAT 5

// Fused zero-fill + scatter. Replaces hipMemsetAsync (which was writing
// out_size*sizeof(float) = 4x the 256 MiB output -- WRITE_SIZE showed exactly
// 1 GiB per fill dispatch) plus the single-workgroup scatter kernel.
//
// Decomposition: 2048 blocks = 128 batches x 2 planes x 8 row-chunks.
// Each block zero-fills its 64-row chunk (32768 floats, coalesced float4
// stores), then __syncthreads() -- hipcc emits s_waitcnt vmcnt(0) before
// s_barrier, so the zeros are at the L2 coherence point before any scatter
// store issues. Thread 0 then replays the batch's 34 receivers IN ORDER
// (last-write-wins for duplicate (y,x), matching the reference's .at[].set
// semantics) and overwrites the few pixels landing in this chunk.

#define CHUNKS_PER_PLANE 8
#define ROWS_PER_CHUNK (IMG / CHUNKS_PER_PLANE)          // 64
#define FLOATS_PER_BLOCK (ROWS_PER_CHUNK * IMG)          // 32768
#define THREADS 256
#define VEC4_PER_THREAD (FLOATS_PER_BLOCK / (THREADS * 4))  // 32

__global__ __launch_bounds__(THREADS)
void Vec2Im_fused_kernel(const float* __restrict__ x_vecs,
                         const float* __restrict__ device_weights,
                         const float* __restrict__ device_bias,
                         const float* __restrict__ category_weights,
                         const float* __restrict__ category_bias,
                         float* __restrict__ out) {
    const int blk   = blockIdx.x;
    const int chunk = blk & (CHUNKS_PER_PLANE - 1);      // low 3 bits
    const int plane = (blk >> 3) & 1;
    const int b     = blk >> 4;

    const size_t plane_start = (size_t)(b * 2 + plane) * (IMG * IMG);
    const size_t chunk_start = plane_start + (size_t)chunk * FLOATS_PER_BLOCK;

    // ---- phase 1: zero-fill this chunk (coalesced, 4 KiB per iteration) ----
    float4* out4 = reinterpret_cast<float4*>(out + chunk_start);
    const float4 z = make_float4(0.f, 0.f, 0.f, 0.f);
    const int tid = threadIdx.x;
#pragma unroll
    for (int i = 0; i < VEC4_PER_THREAD; ++i)
        out4[i * THREADS + tid] = z;

    __syncthreads();  // vmcnt(0) drain: zeros reach L2 before scatter stores

    // ---- phase 2: ordered scatter of the receivers that land here ----
    if (tid == 0) {
        const int row0 = chunk * ROWS_PER_CHUNK;
        // x_vecs row layout: [power, x, y, cat] -> one float4 per receiver
        const float4* xv = reinterpret_cast<const float4*>(x_vecs) + (size_t)b * N_RX;
        for (int r = 0; r < N_RX; ++r) {
            float4 v = xv[r];
            int yy = (int)rintf(v.z);                    // coords[:,:,1]
            if (yy < row0 || yy >= row0 + ROWS_PER_CHUNK) continue;
            int xx = (int)rintf(v.y);                    // coords[:,:,0]
            float raw = v.x;
            float val;
            if (plane == 1) {
                val = raw;                               // raw power plane
            } else {
                float mask = (raw != 0.0f) ? 1.0f : 0.0f;
                float p = raw * device_weights[r] + mask * device_bias[r];
                int cat = (int)v.w;                      // exact small ints
                val = p * category_weights[cat] + mask * category_bias[cat];
            }
            out[plane_start + (size_t)(yy * IMG + xx)] = val;
        }
    }
}

extern "C" void kernel_launch(void* const* d_in, const int* in_sizes, int n_in,
                              void* d_out, int out_size, void* d_ws, size_t ws_size,
                              hipStream_t stream) {
    const float* x_vecs           = (const float*)d_in[0];
    const float* device_weights   = (const float*)d_in[1];
    const float* device_bias      = (const float*)d_in[2];
    const float* category_weights = (const float*)d_in[3];
    const float* category_bias    = (const float*)d_in[4];
    float* out = (float*)d_out;

    // 128 batches x 2 planes x 8 chunks = 2048 blocks; covers all 2^26 floats.
    dim3 grid(B_BATCH * 2 * CHUNKS_PER_PLANE);
    dim3 block(THREADS);
    Vec2Im_fused_kernel<<<grid, block, 0, stream>>>(
        x_vecs, device_weights, device_bias, category_weights, category_bias, out);
}